// Round 16
// baseline (167.018 us; speedup 1.0000x reference)
//
#include <hip/hip_runtime.h>
#include <hip/hip_bf16.h>

#define N 8192
#define IN_F 256
#define HEADS 4
#define HF 64
#define OUT_F 256

typedef __attribute__((ext_vector_type(8))) short short8;
typedef __attribute__((ext_vector_type(4))) float f32x4;
typedef __attribute__((ext_vector_type(2))) float f32x2;

__device__ __forceinline__ float lrelu(float x) {
    return fmaxf(x, 0.0f) * 0.8f + x * 0.2f;
}
__device__ __forceinline__ short f2bf(float f) {
    union { __hip_bfloat16 h; short s; } u;
    u.h = __float2bfloat16(f);
    return u.s;
}
__device__ __forceinline__ float bf2f(unsigned short b) {
    union { unsigned u; float f; } v; v.u = ((unsigned)b) << 16;
    return v.f;
}
__device__ __forceinline__ unsigned pack_bf16(float p0, float p1) {
    union { __hip_bfloat162 b; unsigned u; } cv;
    cv.b = __float22bfloat162_rn(make_float2(p0, p1));
    return cv.u;
}

// direct global->LDS DMA, 16B per lane; LDS dest is wave-uniform base + lane*16
#define GLOAD_LDS(gsrc, ldst) \
    __builtin_amdgcn_global_load_lds( \
        (const __attribute__((address_space(1))) void*)(gsrc), \
        (__attribute__((address_space(3))) void*)(ldst), 16, 0, 0)

#define MFMA16 __builtin_amdgcn_mfma_f32_16x16x32_bf16

// K0: build BbT[c][k] bf16, c<256 -> W heads, c>=256 -> Wr
__global__ __launch_bounds__(256) void k_wcvt(
    const float* __restrict__ w, const float* __restrict__ wr,
    unsigned short* __restrict__ BbT)
{
    int c = blockIdx.x;
    int k = threadIdx.x;
    float v;
    if (c < 256) {
        int head = c >> 6, f = c & 63;
        v = w[((size_t)head * IN_F + k) * HF + f];
    } else {
        v = wr[(size_t)k * OUT_F + (c - 256)];
    }
    BbT[(size_t)c * IN_F + k] = (unsigned short)f2bf(v);
}

// K1: MERGED gemm + pack + fused coe (validated r14 version, unchanged).
__global__ __launch_bounds__(256) void k_gemm_pack(
    const float* __restrict__ x, const unsigned short* __restrict__ BbT,
    const float* __restrict__ bias, const float* __restrict__ wi,
    const float* __restrict__ wj,
    unsigned short* __restrict__ hT, float* __restrict__ out,
    float* __restrict__ coe_i, float* __restrict__ coe_j,
    const int* __restrict__ graph, unsigned int* __restrict__ bits)
{
    __shared__ unsigned short Asw[64 * 64];
    __shared__ unsigned short Bsw[128 * 64];
    int b = blockIdx.x;
    int t = threadIdx.x;

    if (b >= 512) {
        int p = b - 512;
        int jw = p & 255;
        int i = (p >> 8) * 256 + t;
        const int* gp = graph + (size_t)(jw * 32) * N + i;
        unsigned int word = 0;
        #pragma unroll
        for (int k = 0; k < 32; ++k)
            word |= (gp[(size_t)k * N] > 0 ? 1u : 0u) << k;
        bits[(size_t)jw * N + i] = word;
        return;
    }

    int m0 = (b & 127) * 64;
    int bn = b >> 7;
    int w_ = t >> 6, l = t & 63;
    int wr_ = w_ >> 1, wc_ = w_ & 1;
    int ar = l & 15, g = l >> 4;

    f32x4 acc[2][4];
    #pragma unroll
    for (int m = 0; m < 2; ++m)
        #pragma unroll
        for (int n = 0; n < 4; ++n) acc[m][n] = (f32x4){0.f, 0.f, 0.f, 0.f};

    int srow = t >> 2, skq = (t & 3) * 16;
    int sc = t >> 1, sh = (t & 1) * 32;

    for (int kt = 0; kt < 4; ++kt) {
        const float* xs = x + (size_t)(m0 + srow) * IN_F + kt * 64 + skq;
        float4 xa = ((const float4*)xs)[0];
        float4 xb = ((const float4*)xs)[1];
        float4 xc = ((const float4*)xs)[2];
        float4 xd = ((const float4*)xs)[3];
        unsigned ae[8];
        ae[0] = pack_bf16(xa.x, xa.y); ae[1] = pack_bf16(xa.z, xa.w);
        ae[2] = pack_bf16(xb.x, xb.y); ae[3] = pack_bf16(xb.z, xb.w);
        ae[4] = pack_bf16(xc.x, xc.y); ae[5] = pack_bf16(xc.z, xc.w);
        ae[6] = pack_bf16(xd.x, xd.y); ae[7] = pack_bf16(xd.z, xd.w);
        int kb0 = (skq >> 3) ^ (srow & 7);
        int kb1 = ((skq >> 3) + 1) ^ (srow & 7);
        *(uint4*)&Asw[srow * 64 + kb0 * 8] = *(uint4*)&ae[0];
        *(uint4*)&Asw[srow * 64 + kb1 * 8] = *(uint4*)&ae[4];
        const unsigned short* bs = BbT + (size_t)(bn * 128 + sc) * IN_F + kt * 64 + sh;
        uint4 b0 = ((const uint4*)bs)[0];
        uint4 b1 = ((const uint4*)bs)[1];
        uint4 b2 = ((const uint4*)bs)[2];
        uint4 b3 = ((const uint4*)bs)[3];
        int hb = sh >> 3;
        *(uint4*)&Bsw[sc * 64 + ((hb + 0) ^ (sc & 7)) * 8] = b0;
        *(uint4*)&Bsw[sc * 64 + ((hb + 1) ^ (sc & 7)) * 8] = b1;
        *(uint4*)&Bsw[sc * 64 + ((hb + 2) ^ (sc & 7)) * 8] = b2;
        *(uint4*)&Bsw[sc * 64 + ((hb + 3) ^ (sc & 7)) * 8] = b3;
        __syncthreads();
        #pragma unroll
        for (int ks = 0; ks < 2; ++ks) {
            short8 af[2], bf[4];
            #pragma unroll
            for (int m = 0; m < 2; ++m) {
                int row = wr_ * 32 + m * 16 + ar;
                int kb = (ks * 4 + g) ^ (row & 7);
                af[m] = *(const short8*)&Asw[row * 64 + kb * 8];
            }
            #pragma unroll
            for (int n = 0; n < 4; ++n) {
                int c = wc_ * 64 + n * 16 + ar;
                int kb = (ks * 4 + g) ^ (c & 7);
                bf[n] = *(const short8*)&Bsw[c * 64 + kb * 8];
            }
            #pragma unroll
            for (int m = 0; m < 2; ++m)
                #pragma unroll
                for (int n = 0; n < 4; ++n)
                    acc[m][n] = MFMA16(af[m], bf[n], acc[m][n], 0, 0, 0);
        }
        __syncthreads();
    }
    #pragma unroll
    for (int m = 0; m < 2; ++m) {
        #pragma unroll
        for (int n = 0; n < 4; ++n) {
            int cg = bn * 128 + wc_ * 64 + n * 16 + ar;
            int mg0 = m0 + wr_ * 32 + m * 16 + g * 4;
            if (cg < 256) {
                int head = cg >> 6, f = cg & 63;
                unsigned pk[2];
                pk[0] = pack_bf16(acc[m][n][0], acc[m][n][1]);
                pk[1] = pack_bf16(acc[m][n][2], acc[m][n][3]);
                *(uint2*)(hT + (size_t)(head * HF + f) * N + mg0) = *(uint2*)pk;
            } else {
                float bb = bias[cg - 256];
                #pragma unroll
                for (int r = 0; r < 4; ++r)
                    out[(size_t)(mg0 + r) * OUT_F + (cg - 256)] = acc[m][n][r] + bb;
            }
        }
    }
    if (bn < 2) {
        int head = bn * 2 + wc_;
        float pi[2][4], pj[2][4];
        #pragma unroll
        for (int m = 0; m < 2; ++m)
            #pragma unroll
            for (int r = 0; r < 4; ++r) { pi[m][r] = 0.f; pj[m][r] = 0.f; }
        #pragma unroll
        for (int n = 0; n < 4; ++n) {
            float wiv = wi[head * HF + n * 16 + ar];
            float wjv = wj[head * HF + n * 16 + ar];
            #pragma unroll
            for (int m = 0; m < 2; ++m)
                #pragma unroll
                for (int r = 0; r < 4; ++r) {
                    pi[m][r] = fmaf(acc[m][n][r], wiv, pi[m][r]);
                    pj[m][r] = fmaf(acc[m][n][r], wjv, pj[m][r]);
                }
        }
        #pragma unroll
        for (int o = 1; o <= 8; o <<= 1)
            #pragma unroll
            for (int m = 0; m < 2; ++m)
                #pragma unroll
                for (int r = 0; r < 4; ++r) {
                    pi[m][r] += __shfl_xor(pi[m][r], o, 64);
                    pj[m][r] += __shfl_xor(pj[m][r], o, 64);
                }
        if (ar == 0) {
            #pragma unroll
            for (int m = 0; m < 2; ++m)
                #pragma unroll
                for (int r = 0; r < 4; ++r) {
                    int row = m0 + wr_ * 32 + m * 16 + g * 4 + r;
                    coe_i[head * N + row] = pi[m][r];
                    coe_j[head * N + row] = pj[m][r];
                }
        }
    }
}

// K3: per head: maxB + column factor arrays F=exp(b), H=exp(0.2b)
__global__ __launch_bounds__(256) void k_cols(
    const float* __restrict__ coe_j, float* __restrict__ maxB,
    float* __restrict__ F, float* __restrict__ H)
{
    __shared__ float red[256];
    int head = blockIdx.x;
    int t = threadIdx.x;
    float m = -1e30f;
    for (int n = t; n < N; n += 256) {
        float b = coe_j[head * N + n];
        F[head * N + n] = __expf(b);
        H[head * N + n] = __expf(0.2f * b);
        m = fmaxf(m, b);
    }
    red[t] = m;
    __syncthreads();
    for (int s = 128; s > 0; s >>= 1) {
        if (t < s) red[t] = fmaxf(red[t], red[t + s]);
        __syncthreads();
    }
    if (t == 0) maxB[head] = red[0];
}

// P for 8 columns, packed-f32 version: p2 = pk_max(Ei2*F2, Gi2*H2)
// (v_pk_mul_f32 / v_pk_max_f32); mask via sbfe; cvt_pk to bf16.
__device__ __forceinline__ short8 makeP(
    const float4& fa, const float4& fb4, const float4& ha, const float4& hb4,
    unsigned int mk, float Ei, float Gi)
{
    f32x2 fv[4] = {{fa.x, fa.y}, {fa.z, fa.w}, {fb4.x, fb4.y}, {fb4.z, fb4.w}};
    f32x2 hv[4] = {{ha.x, ha.y}, {ha.z, ha.w}, {hb4.x, hb4.y}, {hb4.z, hb4.w}};
    f32x2 E2 = {Ei, Ei};
    f32x2 G2 = {Gi, Gi};
    union { short8 s8; unsigned u[4]; } A;
    #pragma unroll
    for (int jp = 0; jp < 4; ++jp) {
        f32x2 p = __builtin_elementwise_max(E2 * fv[jp], G2 * hv[jp]);
        int s0 = __builtin_amdgcn_sbfe((int)mk, 2 * jp, 1);
        int s1 = __builtin_amdgcn_sbfe((int)mk, 2 * jp + 1, 1);
        float p0 = __int_as_float(__float_as_int(p.x) & s0);
        float p1 = __int_as_float(__float_as_int(p.y) & s1);
        A.u[jp] = pack_bf16(p0, p1);
    }
    return A.s8;
}

__device__ __forceinline__ void merge_write(float* dst, f32x4 (&acc)[4][4], f32x4 (&accd)[4]) {
    #pragma unroll
    for (int rg = 0; rg < 4; ++rg) {
        #pragma unroll
        for (int fb = 0; fb < 4; ++fb)
            #pragma unroll
            for (int r = 0; r < 4; ++r)
                dst[rg * 16 + fb * 4 + r] = acc[rg][fb][r];
        #pragma unroll
        for (int r = 0; r < 4; ++r)
            dst[64 + rg * 4 + r] = accd[rg][r];
    }
}
__device__ __forceinline__ void merge_add(const float* src, f32x4 (&acc)[4][4], f32x4 (&accd)[4]) {
    #pragma unroll
    for (int rg = 0; rg < 4; ++rg) {
        #pragma unroll
        for (int fb = 0; fb < 4; ++fb)
            #pragma unroll
            for (int r = 0; r < 4; ++r)
                acc[rg][fb][r] += src[rg * 16 + fb * 4 + r];
        #pragma unroll
        for (int r = 0; r < 4; ++r)
            accd[rg][r] += src[64 + rg * 4 + r];
    }
}

// one 32-j pipeline step: consume (cm*, cf*) prefetched last step; prefetch
// (nm*, nf*) for step S+1; vmcnt(12) retires everything older than this
// step's 12 issues (incl. gload of buf[S&1]). Pure wave-local ordering.
#define AITER(S, cm0,cm1,cm2,cm3, cfa,cfb,cha,chb, nm0,nm1,nm2,nm3, nfa,nfb,nha,nhb) do { \
    int sn_ = ((S) + 1 < 32) ? (S) + 1 : 0; \
    int jtn_ = j0 + sn_ * 32; \
    _Pragma("unroll") \
    for (int q = 0; q < 4; ++q) \
        GLOAD_LDS(qsrc[q] + jtn_, lbase + (((S) + 1) & 1) * 2048 + q * 512); \
    size_t jwn_ = (size_t)(jtn_ >> 5); \
    nm0 = bbase[jwn_ * N +  0] >> g8; \
    nm1 = bbase[jwn_ * N + 16] >> g8; \
    nm2 = bbase[jwn_ * N + 32] >> g8; \
    nm3 = bbase[jwn_ * N + 48] >> g8; \
    nfa = *(const float4*)(Fp + jtn_); \
    nfb = *(const float4*)(Fp + jtn_ + 4); \
    nha = *(const float4*)(Hp + jtn_); \
    nhb = *(const float4*)(Hp + jtn_ + 4); \
    asm volatile("s_waitcnt vmcnt(12)" ::: "memory"); \
    __builtin_amdgcn_sched_barrier(0); \
    short8 af0 = makeP(cfa, cfb, cha, chb, cm0, Eiv[0], Giv[0]); \
    short8 af1 = makeP(cfa, cfb, cha, chb, cm1, Eiv[1], Giv[1]); \
    short8 af2 = makeP(cfa, cfb, cha, chb, cm2, Eiv[2], Giv[2]); \
    short8 af3 = makeP(cfa, cfb, cha, chb, cm3, Eiv[3], Giv[3]); \
    const unsigned short* rbuf_ = lbase + ((S) & 1) * 2048; \
    _Pragma("unroll") \
    for (int fb = 0; fb < 4; ++fb) { \
        int row_ = fb * 16 + ar; \
        int pg_ = g ^ (ar & 3); \
        short8 bfr_ = *(const short8*)&rbuf_[row_ * 32 + pg_ * 8]; \
        acc[0][fb] = MFMA16(af0, bfr_, acc[0][fb], 0, 0, 0); \
        acc[1][fb] = MFMA16(af1, bfr_, acc[1][fb], 0, 0, 0); \
        acc[2][fb] = MFMA16(af2, bfr_, acc[2][fb], 0, 0, 0); \
        acc[3][fb] = MFMA16(af3, bfr_, acc[3][fb], 0, 0, 0); \
    } \
    accd[0] = MFMA16(af0, ones, accd[0], 0, 0, 0); \
    accd[1] = MFMA16(af1, ones, accd[1], 0, 0, 0); \
    accd[2] = MFMA16(af2, ones, accd[2], 0, 0, 0); \
    accd[3] = MFMA16(af3, ones, accd[3], 0, 0, 0); \
} while (0)

// K5: flash aggregate, per-wave barrier-free pipeline (r15 structure), now
// with 2x-unrolled ping-pong (no rotation movs) + packed-f32 makeP.
__global__ __launch_bounds__(512) void k_att(
    const unsigned short* __restrict__ hT, const float* __restrict__ coe_i,
    const float* __restrict__ maxB, const float* __restrict__ F,
    const float* __restrict__ H, const unsigned int* __restrict__ bits,
    float* __restrict__ out)
{
    __shared__ char smem[65536];

    int t = threadIdx.x;
    int head = blockIdx.y;
    int i0 = blockIdx.x * 64;
    int w = t >> 6, l = t & 63;
    int ar = l & 15, g = l >> 4, g8 = g * 8;

    float mB = maxB[head];
    float Eiv[4], Giv[4];
    #pragma unroll
    for (int rg = 0; rg < 4; ++rg) {
        float a = coe_i[head * N + i0 + rg * 16 + ar];
        float M = lrelu(a + mB);
        Eiv[rg] = __expf(a - M);
        Giv[rg] = __expf(0.2f * a - M);
    }

    f32x4 acc[4][4];
    f32x4 accd[4];
    #pragma unroll
    for (int rg = 0; rg < 4; ++rg) {
        #pragma unroll
        for (int fb = 0; fb < 4; ++fb) acc[rg][fb] = (f32x4){0.f, 0.f, 0.f, 0.f};
        accd[rg] = (f32x4){0.f, 0.f, 0.f, 0.f};
    }

    short8 ones;
    #pragma unroll
    for (int k = 0; k < 8; ++k) ones[k] = (short)0x3F80;

    // private LDS tile: [buf:2][64f][32j], 4KB per buf; swizzle: LDS granule
    // slot p at row f holds global granule p ^ (f&3).
    unsigned short* lbase = (unsigned short*)(smem + w * 8192);
    int srq = l >> 2;
    int sslot = l & 3;
    const unsigned short* qsrc[4];
    #pragma unroll
    for (int q = 0; q < 4; ++q) {
        int row = q * 16 + srq;
        int gg = sslot ^ (row & 3);
        qsrc[q] = hT + (size_t)(head * HF + row) * N + gg * 8;
    }

    const float* Fp = F + head * N + g8;
    const float* Hp = H + head * N + g8;
    const unsigned int* bbase = bits + i0 + ar;

    int j0 = w * 1024;   // private j-range [j0, j0+1024)

    // prolog: stage tile 0 into buf 0; load masks + F/H for tile 0
    #pragma unroll
    for (int q = 0; q < 4; ++q)
        GLOAD_LDS(qsrc[q] + j0, lbase + q * 512);
    unsigned ak0, ak1, ak2, ak3, bk0, bk1, bk2, bk3;
    float4 afa, afb, aha, ahb, bfa, bfb, bha, bhb;
    {
        size_t jw0 = (size_t)(j0 >> 5);
        ak0 = bbase[jw0 * N +  0] >> g8;
        ak1 = bbase[jw0 * N + 16] >> g8;
        ak2 = bbase[jw0 * N + 32] >> g8;
        ak3 = bbase[jw0 * N + 48] >> g8;
        afa = *(const float4*)(Fp + j0);
        afb = *(const float4*)(Fp + j0 + 4);
        aha = *(const float4*)(Hp + j0);
        ahb = *(const float4*)(Hp + j0 + 4);
    }

    #pragma unroll 1
    for (int s = 0; s < 32; s += 2) {
        AITER(s,     ak0,ak1,ak2,ak3, afa,afb,aha,ahb,
                     bk0,bk1,bk2,bk3, bfa,bfb,bha,bhb);
        AITER(s + 1, bk0,bk1,bk2,bk3, bfa,bfb,bha,bhb,
                     ak0,ak1,ak2,ak3, afa,afb,aha,ahb);
    }

    // ---- 8-way merge via LDS (pairwise; first __syncthreads drains all
    // straggler gload_lds DMAs before LDS is reused) ----
    __syncthreads();
    float* fm = (float*)smem;
    int ls = l * 81;
    if (w == 4 || w == 5) merge_write(fm + ((w - 4) * 64 * 81) + ls, acc, accd);
    __syncthreads();
    if (w < 2) merge_add(fm + (w * 64 * 81) + ls, acc, accd);
    __syncthreads();
    if (w == 6 || w == 7) merge_write(fm + ((w - 6) * 64 * 81) + ls, acc, accd);
    __syncthreads();
    if (w == 2 || w == 3) merge_add(fm + ((w - 2) * 64 * 81) + ls, acc, accd);
    __syncthreads();
    if (w == 2 || w == 3) merge_write(fm + ((w - 2) * 64 * 81) + ls, acc, accd);
    __syncthreads();
    if (w < 2) merge_add(fm + (w * 64 * 81) + ls, acc, accd);
    __syncthreads();
    if (w == 1) merge_write(fm + ls, acc, accd);
    __syncthreads();
    if (w == 0) {
        merge_add(fm + ls, acc, accd);
        #pragma unroll
        for (int rg = 0; rg < 4; ++rg) {
            #pragma unroll
            for (int r = 0; r < 4; ++r) {
                float inv = 1.0f / accd[rg][r];
                int orow = i0 + rg * 16 + g * 4 + r;
                float* op = out + (size_t)orow * OUT_F + head * HF + ar;
                #pragma unroll
                for (int fb = 0; fb < 4; ++fb)
                    op[fb * 16] += acc[rg][fb][r] * inv;
            }
        }
    }
}

extern "C" void kernel_launch(void* const* d_in, const int* in_sizes, int n_in,
                              void* d_out, int out_size, void* d_ws, size_t ws_size,
                              hipStream_t stream) {
    const float* x     = (const float*)d_in[0];
    const int*   graph = (const int*)d_in[1];
    const float* w     = (const float*)d_in[2];
    const float* wi    = (const float*)d_in[3];
    const float* wj    = (const float*)d_in[4];
    const float* wr    = (const float*)d_in[5];
    const float* bias  = (const float*)d_in[6];
    float* out = (float*)d_out;

    char* ws = (char*)d_ws;
    unsigned short* hT  = (unsigned short*)(ws);                    // 4,194,304
    float* coe_i = (float*)(ws + 4194304);                          // 131072
    float* coe_j = (float*)(ws + 4325376);                          // 131072
    float* maxB  = (float*)(ws + 4456448);                          // 1024
    float* F     = (float*)(ws + 4457472);                          // 131072
    float* H     = (float*)(ws + 4588544);                          // 131072
    unsigned short* BbT = (unsigned short*)(ws + 4719616);          // 262144
    unsigned int* bits  = (unsigned int*)(ws + 4981760);            // 8,388,608

    k_wcvt<<<dim3(512), 256, 0, stream>>>(w, wr, BbT);
    k_gemm_pack<<<dim3(512 + 8192), 256, 0, stream>>>(x, BbT, bias, wi, wj, hT, out, coe_i, coe_j, graph, bits);
    k_cols<<<dim3(4), 256, 0, stream>>>(coe_j, maxB, F, H);
    k_att<<<dim3(N / 64, HEADS), 512, 0, stream>>>(hT, coe_i, maxB, F, H, bits, out);
}

// Round 17
// 155.976 us; speedup vs baseline: 1.0708x; 1.0708x over previous
//
#include <hip/hip_runtime.h>
#include <hip/hip_bf16.h>

#define N 8192
#define IN_F 256
#define HEADS 4
#define HF 64
#define OUT_F 256

typedef __attribute__((ext_vector_type(8))) short short8;
typedef __attribute__((ext_vector_type(4))) float f32x4;

__device__ __forceinline__ float lrelu(float x) {
    return fmaxf(x, 0.0f) * 0.8f + x * 0.2f;
}
__device__ __forceinline__ short f2bf(float f) {
    union { __hip_bfloat16 h; short s; } u;
    u.h = __float2bfloat16(f);
    return u.s;
}
__device__ __forceinline__ float bf2f(unsigned short b) {
    union { unsigned u; float f; } v; v.u = ((unsigned)b) << 16;
    return v.f;
}
__device__ __forceinline__ unsigned pack_bf16(float p0, float p1) {
    union { __hip_bfloat162 b; unsigned u; } cv;
    cv.b = __float22bfloat162_rn(make_float2(p0, p1));
    return cv.u;
}

// direct global->LDS DMA, 16B per lane; LDS dest is wave-uniform base + lane*16
#define GLOAD_LDS(gsrc, ldst) \
    __builtin_amdgcn_global_load_lds( \
        (const __attribute__((address_space(1))) void*)(gsrc), \
        (__attribute__((address_space(3))) void*)(ldst), 16, 0, 0)

#define MFMA16 __builtin_amdgcn_mfma_f32_16x16x32_bf16

// K0: build BbT[c][k] bf16, c<256 -> W heads, c>=256 -> Wr
__global__ __launch_bounds__(256) void k_wcvt(
    const float* __restrict__ w, const float* __restrict__ wr,
    unsigned short* __restrict__ BbT)
{
    int c = blockIdx.x;
    int k = threadIdx.x;
    float v;
    if (c < 256) {
        int head = c >> 6, f = c & 63;
        v = w[((size_t)head * IN_F + k) * HF + f];
    } else {
        v = wr[(size_t)k * OUT_F + (c - 256)];
    }
    BbT[(size_t)c * IN_F + k] = (unsigned short)f2bf(v);
}

// K1: MERGED gemm + pack + fused coe (validated r14 version, unchanged).
__global__ __launch_bounds__(256) void k_gemm_pack(
    const float* __restrict__ x, const unsigned short* __restrict__ BbT,
    const float* __restrict__ bias, const float* __restrict__ wi,
    const float* __restrict__ wj,
    unsigned short* __restrict__ hT, float* __restrict__ out,
    float* __restrict__ coe_i, float* __restrict__ coe_j,
    const int* __restrict__ graph, unsigned int* __restrict__ bits)
{
    __shared__ unsigned short Asw[64 * 64];
    __shared__ unsigned short Bsw[128 * 64];
    int b = blockIdx.x;
    int t = threadIdx.x;

    if (b >= 512) {
        int p = b - 512;
        int jw = p & 255;
        int i = (p >> 8) * 256 + t;
        const int* gp = graph + (size_t)(jw * 32) * N + i;
        unsigned int word = 0;
        #pragma unroll
        for (int k = 0; k < 32; ++k)
            word |= (gp[(size_t)k * N] > 0 ? 1u : 0u) << k;
        bits[(size_t)jw * N + i] = word;
        return;
    }

    int m0 = (b & 127) * 64;
    int bn = b >> 7;
    int w_ = t >> 6, l = t & 63;
    int wr_ = w_ >> 1, wc_ = w_ & 1;
    int ar = l & 15, g = l >> 4;

    f32x4 acc[2][4];
    #pragma unroll
    for (int m = 0; m < 2; ++m)
        #pragma unroll
        for (int n = 0; n < 4; ++n) acc[m][n] = (f32x4){0.f, 0.f, 0.f, 0.f};

    int srow = t >> 2, skq = (t & 3) * 16;
    int sc = t >> 1, sh = (t & 1) * 32;

    for (int kt = 0; kt < 4; ++kt) {
        const float* xs = x + (size_t)(m0 + srow) * IN_F + kt * 64 + skq;
        float4 xa = ((const float4*)xs)[0];
        float4 xb = ((const float4*)xs)[1];
        float4 xc = ((const float4*)xs)[2];
        float4 xd = ((const float4*)xs)[3];
        unsigned ae[8];
        ae[0] = pack_bf16(xa.x, xa.y); ae[1] = pack_bf16(xa.z, xa.w);
        ae[2] = pack_bf16(xb.x, xb.y); ae[3] = pack_bf16(xb.z, xb.w);
        ae[4] = pack_bf16(xc.x, xc.y); ae[5] = pack_bf16(xc.z, xc.w);
        ae[6] = pack_bf16(xd.x, xd.y); ae[7] = pack_bf16(xd.z, xd.w);
        int kb0 = (skq >> 3) ^ (srow & 7);
        int kb1 = ((skq >> 3) + 1) ^ (srow & 7);
        *(uint4*)&Asw[srow * 64 + kb0 * 8] = *(uint4*)&ae[0];
        *(uint4*)&Asw[srow * 64 + kb1 * 8] = *(uint4*)&ae[4];
        const unsigned short* bs = BbT + (size_t)(bn * 128 + sc) * IN_F + kt * 64 + sh;
        uint4 b0 = ((const uint4*)bs)[0];
        uint4 b1 = ((const uint4*)bs)[1];
        uint4 b2 = ((const uint4*)bs)[2];
        uint4 b3 = ((const uint4*)bs)[3];
        int hb = sh >> 3;
        *(uint4*)&Bsw[sc * 64 + ((hb + 0) ^ (sc & 7)) * 8] = b0;
        *(uint4*)&Bsw[sc * 64 + ((hb + 1) ^ (sc & 7)) * 8] = b1;
        *(uint4*)&Bsw[sc * 64 + ((hb + 2) ^ (sc & 7)) * 8] = b2;
        *(uint4*)&Bsw[sc * 64 + ((hb + 3) ^ (sc & 7)) * 8] = b3;
        __syncthreads();
        #pragma unroll
        for (int ks = 0; ks < 2; ++ks) {
            short8 af[2], bf[4];
            #pragma unroll
            for (int m = 0; m < 2; ++m) {
                int row = wr_ * 32 + m * 16 + ar;
                int kb = (ks * 4 + g) ^ (row & 7);
                af[m] = *(const short8*)&Asw[row * 64 + kb * 8];
            }
            #pragma unroll
            for (int n = 0; n < 4; ++n) {
                int c = wc_ * 64 + n * 16 + ar;
                int kb = (ks * 4 + g) ^ (c & 7);
                bf[n] = *(const short8*)&Bsw[c * 64 + kb * 8];
            }
            #pragma unroll
            for (int m = 0; m < 2; ++m)
                #pragma unroll
                for (int n = 0; n < 4; ++n)
                    acc[m][n] = MFMA16(af[m], bf[n], acc[m][n], 0, 0, 0);
        }
        __syncthreads();
    }
    #pragma unroll
    for (int m = 0; m < 2; ++m) {
        #pragma unroll
        for (int n = 0; n < 4; ++n) {
            int cg = bn * 128 + wc_ * 64 + n * 16 + ar;
            int mg0 = m0 + wr_ * 32 + m * 16 + g * 4;
            if (cg < 256) {
                int head = cg >> 6, f = cg & 63;
                unsigned pk[2];
                pk[0] = pack_bf16(acc[m][n][0], acc[m][n][1]);
                pk[1] = pack_bf16(acc[m][n][2], acc[m][n][3]);
                *(uint2*)(hT + (size_t)(head * HF + f) * N + mg0) = *(uint2*)pk;
            } else {
                float bb = bias[cg - 256];
                #pragma unroll
                for (int r = 0; r < 4; ++r)
                    out[(size_t)(mg0 + r) * OUT_F + (cg - 256)] = acc[m][n][r] + bb;
            }
        }
    }
    if (bn < 2) {
        int head = bn * 2 + wc_;
        float pi[2][4], pj[2][4];
        #pragma unroll
        for (int m = 0; m < 2; ++m)
            #pragma unroll
            for (int r = 0; r < 4; ++r) { pi[m][r] = 0.f; pj[m][r] = 0.f; }
        #pragma unroll
        for (int n = 0; n < 4; ++n) {
            float wiv = wi[head * HF + n * 16 + ar];
            float wjv = wj[head * HF + n * 16 + ar];
            #pragma unroll
            for (int m = 0; m < 2; ++m)
                #pragma unroll
                for (int r = 0; r < 4; ++r) {
                    pi[m][r] = fmaf(acc[m][n][r], wiv, pi[m][r]);
                    pj[m][r] = fmaf(acc[m][n][r], wjv, pj[m][r]);
                }
        }
        #pragma unroll
        for (int o = 1; o <= 8; o <<= 1)
            #pragma unroll
            for (int m = 0; m < 2; ++m)
                #pragma unroll
                for (int r = 0; r < 4; ++r) {
                    pi[m][r] += __shfl_xor(pi[m][r], o, 64);
                    pj[m][r] += __shfl_xor(pj[m][r], o, 64);
                }
        if (ar == 0) {
            #pragma unroll
            for (int m = 0; m < 2; ++m)
                #pragma unroll
                for (int r = 0; r < 4; ++r) {
                    int row = m0 + wr_ * 32 + m * 16 + g * 4 + r;
                    coe_i[head * N + row] = pi[m][r];
                    coe_j[head * N + row] = pj[m][r];
                }
        }
    }
}

// K3: per head: maxB + column factor arrays F=exp(b), H=exp(0.2b)
__global__ __launch_bounds__(256) void k_cols(
    const float* __restrict__ coe_j, float* __restrict__ maxB,
    float* __restrict__ F, float* __restrict__ H)
{
    __shared__ float red[256];
    int head = blockIdx.x;
    int t = threadIdx.x;
    float m = -1e30f;
    for (int n = t; n < N; n += 256) {
        float b = coe_j[head * N + n];
        F[head * N + n] = __expf(b);
        H[head * N + n] = __expf(0.2f * b);
        m = fmaxf(m, b);
    }
    red[t] = m;
    __syncthreads();
    for (int s = 128; s > 0; s >>= 1) {
        if (t < s) red[t] = fmaxf(red[t], red[t + s]);
        __syncthreads();
    }
    if (t == 0) maxB[head] = red[0];
}

// P for 8 columns: p = max(Ei*F, Gi*H) (= exp(lrelu(a+b)-M)); mask via sbfe.
__device__ __forceinline__ short8 makeP(
    const float4& fa, const float4& fb4, const float4& ha, const float4& hb4,
    unsigned int mk, float Ei, float Gi)
{
    float fv[8] = {fa.x, fa.y, fa.z, fa.w, fb4.x, fb4.y, fb4.z, fb4.w};
    float hv[8] = {ha.x, ha.y, ha.z, ha.w, hb4.x, hb4.y, hb4.z, hb4.w};
    union { short8 s8; unsigned u[4]; } A;
    #pragma unroll
    for (int jp = 0; jp < 4; ++jp) {
        float p0 = fmaxf(Ei * fv[2 * jp],     Gi * hv[2 * jp]);
        float p1 = fmaxf(Ei * fv[2 * jp + 1], Gi * hv[2 * jp + 1]);
        int s0 = __builtin_amdgcn_sbfe((int)mk, 2 * jp, 1);
        int s1 = __builtin_amdgcn_sbfe((int)mk, 2 * jp + 1, 1);
        p0 = __int_as_float(__float_as_int(p0) & s0);
        p1 = __int_as_float(__float_as_int(p1) & s1);
        A.u[jp] = pack_bf16(p0, p1);
    }
    return A.s8;
}

__device__ __forceinline__ void merge_write(float* dst, f32x4 (&acc)[4][4], f32x4 (&accd)[4]) {
    #pragma unroll
    for (int rg = 0; rg < 4; ++rg) {
        #pragma unroll
        for (int fb = 0; fb < 4; ++fb)
            #pragma unroll
            for (int r = 0; r < 4; ++r)
                dst[rg * 16 + fb * 4 + r] = acc[rg][fb][r];
        #pragma unroll
        for (int r = 0; r < 4; ++r)
            dst[64 + rg * 4 + r] = accd[rg][r];
    }
}
__device__ __forceinline__ void merge_add(const float* src, f32x4 (&acc)[4][4], f32x4 (&accd)[4]) {
    #pragma unroll
    for (int rg = 0; rg < 4; ++rg) {
        #pragma unroll
        for (int fb = 0; fb < 4; ++fb)
            #pragma unroll
            for (int r = 0; r < 4; ++r)
                acc[rg][fb][r] += src[rg * 16 + fb * 4 + r];
        #pragma unroll
        for (int r = 0; r < 4; ++r)
            accd[rg][r] += src[64 + rg * 4 + r];
    }
}

// K5: flash aggregate, PER-WAVE BARRIER-FREE pipeline (r15 verbatim — best
// measured: 156.4 µs total). Each wave: M=64 output rows x private 1024-j
// range, private 64f x 32j double-buffered LDS tile (8KB/wave). Per iter:
// issue 12 VMEM prefetches for s+1 (4 gload_lds + 4 masks + 4 F/H), then
// s_waitcnt vmcnt(12) — FIFO retire means everything older (incl. gload(s))
// is complete. No __syncthreads in the main loop; 8-way merge at the end.
__global__ __launch_bounds__(512) void k_att(
    const unsigned short* __restrict__ hT, const float* __restrict__ coe_i,
    const float* __restrict__ maxB, const float* __restrict__ F,
    const float* __restrict__ H, const unsigned int* __restrict__ bits,
    float* __restrict__ out)
{
    __shared__ char smem[65536];

    int t = threadIdx.x;
    int head = blockIdx.y;
    int i0 = blockIdx.x * 64;
    int w = t >> 6, l = t & 63;
    int ar = l & 15, g = l >> 4, g8 = g * 8;

    float mB = maxB[head];
    float Eiv[4], Giv[4];
    #pragma unroll
    for (int rg = 0; rg < 4; ++rg) {
        float a = coe_i[head * N + i0 + rg * 16 + ar];
        float M = lrelu(a + mB);
        Eiv[rg] = __expf(a - M);
        Giv[rg] = __expf(0.2f * a - M);
    }

    f32x4 acc[4][4];
    f32x4 accd[4];
    #pragma unroll
    for (int rg = 0; rg < 4; ++rg) {
        #pragma unroll
        for (int fb = 0; fb < 4; ++fb) acc[rg][fb] = (f32x4){0.f, 0.f, 0.f, 0.f};
        accd[rg] = (f32x4){0.f, 0.f, 0.f, 0.f};
    }

    short8 ones;
    #pragma unroll
    for (int k = 0; k < 8; ++k) ones[k] = (short)0x3F80;

    // private LDS tile: [buf:2][64f][32j], 4KB per buf; swizzle: LDS granule
    // slot p at row f holds global granule p ^ (f&3).
    unsigned short* lbase = (unsigned short*)(smem + w * 8192);
    // gload q stages rows q*16 + (l>>2), granule slot l&3 (1KB per gload)
    int srq = l >> 2;
    int sslot = l & 3;
    const unsigned short* qsrc[4];
    #pragma unroll
    for (int q = 0; q < 4; ++q) {
        int row = q * 16 + srq;
        int gg = sslot ^ (row & 3);
        qsrc[q] = hT + (size_t)(head * HF + row) * N + gg * 8;
    }

    const float* Fp = F + head * N + g8;
    const float* Hp = H + head * N + g8;
    const unsigned int* bbase = bits + i0 + ar;

    int j0 = w * 1024;   // private j-range [j0, j0+1024)

    // prolog: stage tile 0 into buf 0; load masks + F/H for tile 0
    #pragma unroll
    for (int q = 0; q < 4; ++q)
        GLOAD_LDS(qsrc[q] + j0, lbase + q * 512);
    unsigned mk0, mk1, mk2, mk3;
    float4 cfa, cfb, cha, chb;
    {
        size_t jw0 = (size_t)(j0 >> 5);
        mk0 = bbase[jw0 * N +  0] >> g8;
        mk1 = bbase[jw0 * N + 16] >> g8;
        mk2 = bbase[jw0 * N + 32] >> g8;
        mk3 = bbase[jw0 * N + 48] >> g8;
        cfa = *(const float4*)(Fp + j0);
        cfb = *(const float4*)(Fp + j0 + 4);
        cha = *(const float4*)(Hp + j0);
        chb = *(const float4*)(Hp + j0 + 4);
    }

    #pragma unroll 1
    for (int s = 0; s < 32; ++s) {
        int sn = (s + 1 < 32) ? s + 1 : 0;     // last iter wraps (discarded)
        int jtn = j0 + sn * 32;
        // issue next tile's 12 VMEM prefetches
        #pragma unroll
        for (int q = 0; q < 4; ++q)
            GLOAD_LDS(qsrc[q] + jtn, lbase + ((s + 1) & 1) * 2048 + q * 512);
        size_t jwn = (size_t)(jtn >> 5);
        unsigned nk0 = bbase[jwn * N +  0] >> g8;
        unsigned nk1 = bbase[jwn * N + 16] >> g8;
        unsigned nk2 = bbase[jwn * N + 32] >> g8;
        unsigned nk3 = bbase[jwn * N + 48] >> g8;
        float4 nfa = *(const float4*)(Fp + jtn);
        float4 nfb = *(const float4*)(Fp + jtn + 4);
        float4 nha = *(const float4*)(Hp + jtn);
        float4 nhb = *(const float4*)(Hp + jtn + 4);

        // wait: <=12 outstanding VMEM -> everything older (gload(s), mask(s),
        // F/H(s)) retired. No barrier; wave-local only.
        asm volatile("s_waitcnt vmcnt(12)" ::: "memory");
        __builtin_amdgcn_sched_barrier(0);

        // A-fragments from current (prefetched) inputs
        short8 af0 = makeP(cfa, cfb, cha, chb, mk0, Eiv[0], Giv[0]);
        short8 af1 = makeP(cfa, cfb, cha, chb, mk1, Eiv[1], Giv[1]);
        short8 af2 = makeP(cfa, cfb, cha, chb, mk2, Eiv[2], Giv[2]);
        short8 af3 = makeP(cfa, cfb, cha, chb, mk3, Eiv[3], Giv[3]);

        // ds_read B-frags from buf[s&1]; each feeds 4 row-group MFMAs
        const unsigned short* rbuf = lbase + (s & 1) * 2048;
        #pragma unroll
        for (int fb = 0; fb < 4; ++fb) {
            int row = fb * 16 + ar;
            int pg = g ^ (ar & 3);
            short8 bfr = *(const short8*)&rbuf[row * 32 + pg * 8];
            acc[0][fb] = MFMA16(af0, bfr, acc[0][fb], 0, 0, 0);
            acc[1][fb] = MFMA16(af1, bfr, acc[1][fb], 0, 0, 0);
            acc[2][fb] = MFMA16(af2, bfr, acc[2][fb], 0, 0, 0);
            acc[3][fb] = MFMA16(af3, bfr, acc[3][fb], 0, 0, 0);
        }
        accd[0] = MFMA16(af0, ones, accd[0], 0, 0, 0);
        accd[1] = MFMA16(af1, ones, accd[1], 0, 0, 0);
        accd[2] = MFMA16(af2, ones, accd[2], 0, 0, 0);
        accd[3] = MFMA16(af3, ones, accd[3], 0, 0, 0);

        // rotate prefetched inputs
        mk0 = nk0; mk1 = nk1; mk2 = nk2; mk3 = nk3;
        cfa = nfa; cfb = nfb; cha = nha; chb = nhb;
    }

    // ---- 8-way merge via LDS (pairwise, 2 writers per sub-round) ----
    __syncthreads();   // all waves done with private tiles
    float* fm = (float*)smem;
    int ls = l * 81;
    // R1a: w0+=w4, w1+=w5
    if (w == 4 || w == 5) merge_write(fm + ((w - 4) * 64 * 81) + ls, acc, accd);
    __syncthreads();
    if (w < 2) merge_add(fm + (w * 64 * 81) + ls, acc, accd);
    __syncthreads();
    // R1b: w2+=w6, w3+=w7
    if (w == 6 || w == 7) merge_write(fm + ((w - 6) * 64 * 81) + ls, acc, accd);
    __syncthreads();
    if (w == 2 || w == 3) merge_add(fm + ((w - 2) * 64 * 81) + ls, acc, accd);
    __syncthreads();
    // R2: w0+=w2, w1+=w3
    if (w == 2 || w == 3) merge_write(fm + ((w - 2) * 64 * 81) + ls, acc, accd);
    __syncthreads();
    if (w < 2) merge_add(fm + (w * 64 * 81) + ls, acc, accd);
    __syncthreads();
    // R3: w0+=w1
    if (w == 1) merge_write(fm + ls, acc, accd);
    __syncthreads();
    if (w == 0) {
        merge_add(fm + ls, acc, accd);
        #pragma unroll
        for (int rg = 0; rg < 4; ++rg) {
            #pragma unroll
            for (int r = 0; r < 4; ++r) {
                float inv = 1.0f / accd[rg][r];
                int orow = i0 + rg * 16 + g * 4 + r;
                float* op = out + (size_t)orow * OUT_F + head * HF + ar;
                #pragma unroll
                for (int fb = 0; fb < 4; ++fb)
                    op[fb * 16] += acc[rg][fb][r] * inv;
            }
        }
    }
}

extern "C" void kernel_launch(void* const* d_in, const int* in_sizes, int n_in,
                              void* d_out, int out_size, void* d_ws, size_t ws_size,
                              hipStream_t stream) {
    const float* x     = (const float*)d_in[0];
    const int*   graph = (const int*)d_in[1];
    const float* w     = (const float*)d_in[2];
    const float* wi    = (const float*)d_in[3];
    const float* wj    = (const float*)d_in[4];
    const float* wr    = (const float*)d_in[5];
    const float* bias  = (const float*)d_in[6];
    float* out = (float*)d_out;

    char* ws = (char*)d_ws;
    unsigned short* hT  = (unsigned short*)(ws);                    // 4,194,304
    float* coe_i = (float*)(ws + 4194304);                          // 131072
    float* coe_j = (float*)(ws + 4325376);                          // 131072
    float* maxB  = (float*)(ws + 4456448);                          // 1024
    float* F     = (float*)(ws + 4457472);                          // 131072
    float* H     = (float*)(ws + 4588544);                          // 131072
    unsigned short* BbT = (unsigned short*)(ws + 4719616);          // 262144
    unsigned int* bits  = (unsigned int*)(ws + 4981760);            // 8,388,608

    k_wcvt<<<dim3(512), 256, 0, stream>>>(w, wr, BbT);
    k_gemm_pack<<<dim3(512 + 8192), 256, 0, stream>>>(x, BbT, bias, wi, wj, hT, out, coe_i, coe_j, graph, bits);
    k_cols<<<dim3(4), 256, 0, stream>>>(coe_j, maxB, F, H);
    k_att<<<dim3(N / 64, HEADS), 512, 0, stream>>>(hT, coe_i, maxB, F, H, bits, out);
}